// Round 8
// baseline (322.543 us; speedup 1.0000x reference)
//
#include <hip/hip_runtime.h>
#include <hip/hip_bf16.h>
#include <math.h>

#define N_NODES 50000
#define N_EDGES 1600000
#define ET (N_EDGES + N_NODES)   // with self loops
#define IN_C 165
#define HID 256
#define HEADS 8
#define C1 32
#define OUT_C 2
#define NEG_SLOPE 0.2f
#define LOG2E 1.44269504088896f
#define TROWS 32                           // gemm tile rows (mfma 32x32)
#define GEMM_BLOCKS ((N_NODES + TROWS - 1) / TROWS)  // 1563
#define SCB 2048                           // scatter blocks (8 classes x 256)
#define SGRP 256                           // scatter blocks per class
#define NPP ((N_NODES + 7) / 8)            // 6250 nodes per dst partition
#define CAPL 96                            // fixed per-node list capacity
#define NE4 (N_EDGES / 4)                  // 400000 int4-scan elements

// ---- MFMA gemm geometry ----
// K padded 165 -> 176 = 11 steps of K16 (v_mfma_f32_32x32x16_bf16).
// bf16x3 split: X*W ~= xh*wh + xh*wl + xl*wh  (xl*wl ~2^-18 rel, dropped).
// x converted per-block into LDS (no big xImg); B read straight from a
// 176KB L2-hot fragment-major image; attention dots folded into MFMA via
// Wa = W*att (a = x*(W*att) = h*att exactly, associativity).
#define NSTEP 11
#define BIMG_BYTES ((size_t)NSTEP * 16384)                 // 176 KB
#define WAIMG_BYTES ((size_t)NSTEP * 2048)                 // 22.5 KB
#define WT (NSTEP * 512)                   // W granules: (s, kg, nsub, col32)
#define WPB ((WT + 255) / 256)             // 22
#define WAT (176 * 16)                     // Wa dots: (k, j)
#define WAB ((WAT + 255) / 256)            // 11

typedef float f32x2 __attribute__((ext_vector_type(2)));
typedef short s16x8 __attribute__((ext_vector_type(8)));
typedef float f32x16 __attribute__((ext_vector_type(16)));

__device__ inline float lrelu(float v) { return v > 0.f ? v : NEG_SLOPE * v; }
// weight from PRE-SCALED (x log2e) logit: exp(lrelu(x)) = exp2(lrelu(x*log2e))
__device__ inline float e2l(float t) { return exp2f(fmaxf(t, NEG_SLOPE * t)); }

// fp32 -> bf16 bits, round-to-nearest-even
__device__ inline unsigned short f32_bf16(float f) {
    unsigned u = __float_as_uint(f);
    return (unsigned short)((u + 0x7FFFu + ((u >> 16) & 1u)) >> 16);
}

__device__ inline float bflo(unsigned u) { return __uint_as_float(u << 16); }
__device__ inline float bfhi(unsigned u) { return __uint_as_float(u & 0xFFFF0000u); }
__device__ inline float bf2f(unsigned short b) { return __uint_as_float(((unsigned)b) << 16); }

// ============ prepass: W fragment image + Wa (= W*att) fragment image =======
__global__ __launch_bounds__(256) void prep_kernel(
        const float* __restrict__ W,
        const float* __restrict__ att_src, const float* __restrict__ att_dst,
        unsigned short* __restrict__ bImg, unsigned short* __restrict__ waImg) {
    if (blockIdx.x < WPB) {
        int g2 = blockIdx.x * 256 + threadIdx.x;
        if (g2 >= WT) return;
        int s = g2 >> 9;
        int r9 = g2 & 511;
        int kg = r9 >> 8, nsub = (r9 >> 5) & 7, c32 = r9 & 31;
        int col = nsub * 32 + c32;
        int k0 = s * 16 + kg * 8;
        unsigned short hb[8], lb[8];
        #pragma unroll
        for (int i = 0; i < 8; ++i) {
            int k = k0 + i;
            float v = (k < IN_C) ? W[(size_t)k * HID + col] : 0.f;
            hb[i] = f32_bf16(v);
            lb[i] = f32_bf16(v - bf2f(hb[i]));
        }
        unsigned ph[4], pl[4];
        #pragma unroll
        for (int q = 0; q < 4; ++q) {
            ph[q] = (unsigned)hb[2*q] | ((unsigned)hb[2*q+1] << 16);
            pl[q] = (unsigned)lb[2*q] | ((unsigned)lb[2*q+1] << 16);
        }
        unsigned short* base = bImg + (size_t)s * 8192
                             + ((nsub * 2 + kg) * 32 + c32) * 8;
        *(uint4*)(base)        = make_uint4(ph[0], ph[1], ph[2], ph[3]);
        *(uint4*)(base + 4096) = make_uint4(pl[0], pl[1], pl[2], pl[3]);
    } else {
        int g2 = (blockIdx.x - WPB) * 256 + threadIdx.x;
        if (g2 >= WAT) return;
        int k = g2 >> 4, j = g2 & 15;
        int head = j >> 1;
        float dotv = 0.f;
        if (k < IN_C) {
            const float* wr = W + (size_t)k * HID + head * 32;
            const float* at = ((j & 1) ? att_dst : att_src) + head * 32;
            #pragma unroll
            for (int c = 0; c < 32; c += 4) {
                float4 wv = *(const float4*)(wr + c);
                float4 av = *(const float4*)(at + c);
                dotv += wv.x*av.x + wv.y*av.y + wv.z*av.z + wv.w*av.w;
            }
        }
        unsigned short dh = f32_bf16(dotv);
        unsigned short dl = f32_bf16(dotv - bf2f(dh));
        int s = k >> 4, kk = k & 15, kg = kk >> 3, i = kk & 7;
        unsigned short* base = waImg + (size_t)s * 1024 + (kg * 32 + j) * 8 + i;
        base[0]   = dh;     // split h
        base[512] = dl;     // split l
    }
}

// ============ MFMA gemm1 + fused attention-dot tiles ============
// Block = 32 rows x 256 cols, 4 waves; wave w owns cols w*64..w*64+63.
// Frag layouts: A lane l -> row=l&31, k=(l>>5)*8+i; B lane l -> col=l&31,
// k=(l>>5)*8+i; D lane l,reg r -> col=l&31, row=(r&3)+8*(r>>2)+4*(l>>5).
__device__ __forceinline__ void gemm_mfma_block(
        int b, const float* __restrict__ x,
        const unsigned short* __restrict__ bImg,
        const unsigned short* __restrict__ waImg,
        unsigned short* __restrict__ h, float* __restrict__ a_src,
        float* __restrict__ a_dst, unsigned short* asr) {
    const int tid = threadIdx.x;
    const int w = tid >> 6, l = tid & 63;
    const int half = l >> 5, ln = l & 31;
    const int row0 = b * TROWS;
    // ---- convert x slab -> fragment-major split-bf16 A region in LDS ----
    for (int g = tid; g < 704; g += 256) {
        int o = g >> 5, row = g & 31;
        int s = o >> 1, kg = o & 1;
        int node = row0 + row;
        int k0 = o * 8;
        unsigned short hb[8], lb[8];
        #pragma unroll
        for (int i = 0; i < 8; ++i) {
            int k = k0 + i;
            float v = (node < N_NODES && k < IN_C) ? x[(size_t)node * IN_C + k] : 0.f;
            hb[i] = f32_bf16(v);
            lb[i] = f32_bf16(v - bf2f(hb[i]));
        }
        unsigned ph[4], pl[4];
        #pragma unroll
        for (int q = 0; q < 4; ++q) {
            ph[q] = (unsigned)hb[2*q] | ((unsigned)hb[2*q+1] << 16);
            pl[q] = (unsigned)lb[2*q] | ((unsigned)lb[2*q+1] << 16);
        }
        unsigned short* base = asr + s * 1024 + (kg * 32 + row) * 8;
        *(uint4*)(base)       = make_uint4(ph[0], ph[1], ph[2], ph[3]);
        *(uint4*)(base + 512) = make_uint4(pl[0], pl[1], pl[2], pl[3]);
    }
    __syncthreads();

    f32x16 acc0, acc1, accA;
    #pragma unroll
    for (int r = 0; r < 16; ++r) { acc0[r] = 0.f; acc1[r] = 0.f; accA[r] = 0.f; }
    const int ns0 = 2 * w, ns1 = 2 * w + 1;
    const int afo = (half * 32 + ln) * 8;     // A/Wa frag offset (shorts)
    const int fo0 = ((ns0 * 2 + half) * 32 + ln) * 8;
    const int fo1 = ((ns1 * 2 + half) * 32 + ln) * 8;
    for (int s = 0; s < NSTEP; ++s) {
        const unsigned short* ab = asr + s * 1024;
        s16x8 a_h = *(const s16x8*)(ab + afo);
        s16x8 a_l = *(const s16x8*)(ab + 512 + afo);
        const unsigned short* bb = bImg + (size_t)s * 8192;
        s16x8 bh0 = *(const s16x8*)(bb + fo0);
        s16x8 bh1 = *(const s16x8*)(bb + fo1);
        s16x8 bl0 = *(const s16x8*)(bb + 4096 + fo0);
        s16x8 bl1 = *(const s16x8*)(bb + 4096 + fo1);
        acc0 = __builtin_amdgcn_mfma_f32_32x32x16_bf16(a_h, bh0, acc0, 0, 0, 0);
        acc1 = __builtin_amdgcn_mfma_f32_32x32x16_bf16(a_h, bh1, acc1, 0, 0, 0);
        acc0 = __builtin_amdgcn_mfma_f32_32x32x16_bf16(a_h, bl0, acc0, 0, 0, 0);
        acc1 = __builtin_amdgcn_mfma_f32_32x32x16_bf16(a_h, bl1, acc1, 0, 0, 0);
        acc0 = __builtin_amdgcn_mfma_f32_32x32x16_bf16(a_l, bh0, acc0, 0, 0, 0);
        acc1 = __builtin_amdgcn_mfma_f32_32x32x16_bf16(a_l, bh1, acc1, 0, 0, 0);
        if (w == 0) {                          // wave-uniform branch
            const unsigned short* wb = waImg + (size_t)s * 1024;
            s16x8 wah = *(const s16x8*)(wb + afo);
            s16x8 wal = *(const s16x8*)(wb + 512 + afo);
            accA = __builtin_amdgcn_mfma_f32_32x32x16_bf16(a_h, wah, accA, 0, 0, 0);
            accA = __builtin_amdgcn_mfma_f32_32x32x16_bf16(a_h, wal, accA, 0, 0, 0);
            accA = __builtin_amdgcn_mfma_f32_32x32x16_bf16(a_l, wah, accA, 0, 0, 0);
        }
    }
    // ---- epilogue: h (bf16) stores ----
    #pragma unroll
    for (int t = 0; t < 2; ++t) {
        const int colg = w * 64 + t * 32 + ln;
        #pragma unroll
        for (int r = 0; r < 16; ++r) {
            int row = (r & 3) + 8 * (r >> 2) + 4 * half;
            int gr = row0 + row;
            if (gr < N_NODES) {
                float a = t ? acc1[r] : acc0[r];
                h[(size_t)gr * HID + colg] = f32_bf16(a);
            }
        }
    }
    // ---- epilogue: attention logits straight from the Wa tile ----
    if (w == 0 && ln < 16) {
        int head = ln >> 1;
        float* ap = (ln & 1) ? a_dst : a_src;
        #pragma unroll
        for (int r = 0; r < 16; ++r) {
            int row = (r & 3) + 8 * (r >> 2) + 4 * half;
            int gr = row0 + row;
            if (gr < N_NODES) ap[gr * 8 + head] = accA[r] * LOG2E;
        }
    }
}

// ============ fused: MFMA gemm || partition-filtered slotted scatter ========
__global__ __launch_bounds__(256) void fusedAB_kernel(
        const float* __restrict__ x,
        const unsigned short* __restrict__ bImg,
        const unsigned short* __restrict__ waImg,
        unsigned short* __restrict__ h, float* __restrict__ a_src,
        float* __restrict__ a_dst,
        const int* __restrict__ src, const int* __restrict__ dst,
        int* __restrict__ deg, unsigned short* __restrict__ csr) {
    __shared__ unsigned short asr[NSTEP * 1024];   // 22.5 KB A-fragment region
    if (blockIdx.x < GEMM_BLOCKS) {
        gemm_mfma_block(blockIdx.x, x, bImg, waImg, h, a_src, a_dst, asr);
    } else {
        const int sb  = blockIdx.x - GEMM_BLOCKS;   // 0..SCB-1
        const int cls = sb & 7;
        const int blk = sb >> 3;                    // 0..255 within class
        const int lo = cls * NPP;
        const int hi = (lo + NPP < N_NODES) ? lo + NPP : N_NODES;
        const int t = blk * 256 + threadIdx.x;      // 0..65535 within class
        if (t < hi - lo) {                          // self loops: direct insert
            int d = lo + t;
            int slot = atomicAdd(&deg[d], 1);
            csr[(size_t)d * CAPL + slot] = (unsigned short)d;
        }
        const int4* dst4 = (const int4*)dst;        // int4 scan of real edges
        for (int uu = t; uu < NE4; uu += SGRP * 256) {
            int4 dv = dst4[uu];
            #pragma unroll
            for (int j = 0; j < 4; ++j) {
                int d = (j == 0) ? dv.x : (j == 1) ? dv.y : (j == 2) ? dv.z : dv.w;
                if (d >= lo && d < hi) {
                    int slot = atomicAdd(&deg[d], 1);
                    csr[(size_t)d * CAPL + slot] = (unsigned short)src[4 * uu + j];
                }
            }
        }
    }
}

// ============ Layer 1 fused: softmax-aggregate(bf16 gather) + bias + ELU
//              + layer-2 GEMM.  R8: edge list held in REGISTERS (uint4 pairs,
//              wave-uniform, 1-round prefetch) — zero list VMEM in the loop;
//              all 8 h1-gathers + 8 weight loads issue immediately from
//              register-extracted indices. Masked edges clamp s -> wid
//              (always-valid row) so 0-weight x garbage can't make NaN. ====
__global__ __launch_bounds__(256) void agg1_fused_kernel(
        const int* __restrict__ deg, const unsigned short* __restrict__ csr,
        const float* __restrict__ a_src, const float* __restrict__ a_dst,
        const unsigned short* __restrict__ h1, const float* __restrict__ bias1,
        const float* __restrict__ W2,
        const float* __restrict__ as2, const float* __restrict__ ad2,
        float4* __restrict__ pk, float* __restrict__ a2d) {
    int wid = (blockIdx.x * 256 + threadIdx.x) >> 6;
    int l = threadIdx.x & 63;
    if (wid >= N_NODES) return;
    const int el = l >> 5;                    // edge parity (half-wave)
    const int q  = l & 31;                    // channel octet id
    const int hd = q >> 2;                    // head
    const int ch = q * 8;                     // ushort offset (16 B per lane)
    const int sh = el * 16;                   // halfword select shift
    const uint4* lst4 = (const uint4*)(csr + (size_t)wid * CAPL);
    const int n = deg[wid];
    const float ad_p = a_dst[wid * 8 + hd];
    float den = 0.f;
    f32x2 ac0 = {0.f, 0.f}, ac1 = {0.f, 0.f}, ac2 = {0.f, 0.f}, ac3 = {0.f, 0.f};
    uint4 ca = lst4[0], cb = lst4[1];         // edges 0..15 (CAPL region valid)
    for (int i = 0; i < n; i += 16) {
        uint4 na = ca, nb = cb;
        if (i + 16 < n) {                     // prefetch next 16-edge pair
            na = lst4[(i >> 3) + 2];
            nb = lst4[(i >> 3) + 3];
        }
        // extract this round's 8 per-halfwave edge indices from registers
        int s[8]; float mk[8];
        #pragma unroll
        for (int j = 0; j < 8; ++j) {
            unsigned wsel;
            switch (j) {
                case 0: wsel = ca.x; break; case 1: wsel = ca.y; break;
                case 2: wsel = ca.z; break; case 3: wsel = ca.w; break;
                case 4: wsel = cb.x; break; case 5: wsel = cb.y; break;
                case 6: wsel = cb.z; break; default: wsel = cb.w; break;
            }
            int sv = (int)((wsel >> sh) & 0xFFFFu);
            int e = i + 2 * j + el;
            bool ok = e < n;
            mk[j] = ok ? 1.f : 0.f;
            s[j] = ok ? sv : wid;             // clamp: valid row, weight 0
        }
        uint4 v[8];
        #pragma unroll
        for (int j = 0; j < 8; ++j)
            v[j] = *(const uint4*)(h1 + (size_t)s[j] * HID + ch);
        float w[8];
        #pragma unroll
        for (int j = 0; j < 8; ++j)
            w[j] = mk[j] * e2l(a_src[s[j] * 8 + hd] + ad_p);
        #pragma unroll
        for (int j = 0; j < 8; ++j) {
            den += w[j];
            f32x2 w2 = {w[j], w[j]};
            ac0 += w2 * (f32x2){bflo(v[j].x), bfhi(v[j].x)};
            ac1 += w2 * (f32x2){bflo(v[j].y), bfhi(v[j].y)};
            ac2 += w2 * (f32x2){bflo(v[j].z), bfhi(v[j].z)};
            ac3 += w2 * (f32x2){bflo(v[j].w), bfhi(v[j].w)};
        }
        ca = na; cb = nb;
    }
    float accs[8] = {ac0.x, ac0.y, ac1.x, ac1.y, ac2.x, ac2.y, ac3.x, ac3.y};
    den += __shfl_xor(den, 32);
    #pragma unroll
    for (int k = 0; k < 8; ++k) accs[k] += __shfl_xor(accs[k], 32);

    const float inv = 1.f / den;
    float4 bva = *(const float4*)(bias1 + ch);
    float4 bvb = *(const float4*)(bias1 + ch + 4);
    float o[8];
    o[0] = accs[0] * inv + bva.x; o[1] = accs[1] * inv + bva.y;
    o[2] = accs[2] * inv + bva.z; o[3] = accs[3] * inv + bva.w;
    o[4] = accs[4] * inv + bvb.x; o[5] = accs[5] * inv + bvb.y;
    o[6] = accs[6] * inv + bvb.z; o[7] = accs[7] * inv + bvb.w;
    #pragma unroll
    for (int k = 0; k < 8; ++k) o[k] = o[k] > 0.f ? o[k] : expm1f(o[k]);
    const float* wv = W2 + q * 16;
    float4 w0 = *(const float4*)(wv);
    float4 w1 = *(const float4*)(wv + 4);
    float4 w2 = *(const float4*)(wv + 8);
    float4 w3 = *(const float4*)(wv + 12);
    float p0 = o[0]*w0.x + o[1]*w0.z + o[2]*w1.x + o[3]*w1.z
             + o[4]*w2.x + o[5]*w2.z + o[6]*w3.x + o[7]*w3.z;
    float p1 = o[0]*w0.y + o[1]*w0.w + o[2]*w1.y + o[3]*w1.w
             + o[4]*w2.y + o[5]*w2.w + o[6]*w3.y + o[7]*w3.w;
    #pragma unroll
    for (int off = 16; off; off >>= 1) {
        p0 += __shfl_xor(p0, off);
        p1 += __shfl_xor(p1, off);
    }
    if (l == 0) {
        pk[wid] = make_float4(p0, p1, (p0 * as2[0] + p1 * as2[1]) * LOG2E, 0.f);
        a2d[wid] = (p0 * ad2[0] + p1 * ad2[1]) * LOG2E;
    }
}

// ============ Layer 2 fused (unchanged) ============
__global__ __launch_bounds__(256) void agg2_fused_kernel(
        const int* __restrict__ deg, const unsigned short* __restrict__ csr,
        const float4* __restrict__ pk, const float* __restrict__ a2d,
        const float* __restrict__ b2, float* __restrict__ out) {
    int t = blockIdx.x * 256 + threadIdx.x;
    int node = t >> 4;
    int l = t & 15;
    if (node >= N_NODES) return;
    const unsigned short* lst = csr + (size_t)node * CAPL;
    const int n = deg[node];
    const float adv = a2d[node];
    float sm = 0.f, acc0 = 0.f, acc1 = 0.f;
    for (int i = l; i < n; i += 64) {
        int s[4]; float mk[4];
        #pragma unroll
        for (int j = 0; j < 4; ++j) {
            int e = i + 16 * j;
            mk[j] = (e < n) ? 1.f : 0.f;
            s[j] = lst[(e < n) ? e : (n - 1)];
        }
        float4 pv[4];
        #pragma unroll
        for (int j = 0; j < 4; ++j) pv[j] = pk[s[j]];
        #pragma unroll
        for (int j = 0; j < 4; ++j) {
            float w = mk[j] * e2l(pv[j].z + adv);
            sm += w;
            acc0 += w * pv[j].x;
            acc1 += w * pv[j].y;
        }
    }
    #pragma unroll
    for (int off = 8; off; off >>= 1) {
        sm   += __shfl_xor(sm, off);
        acc0 += __shfl_xor(acc0, off);
        acc1 += __shfl_xor(acc1, off);
    }
    if (l == 0) {
        *(float2*)(out + node * 2) =
            make_float2(acc0 / sm + b2[0], acc1 / sm + b2[1]);
    }
}

extern "C" void kernel_launch(void* const* d_in, const int* in_sizes, int n_in,
                              void* d_out, int out_size, void* d_ws, size_t ws_size,
                              hipStream_t stream) {
    (void)in_sizes; (void)n_in; (void)out_size; (void)ws_size;
    const float* x        = (const float*)d_in[0];
    const int*   ei       = (const int*)d_in[1];
    const float* W1       = (const float*)d_in[2];
    const float* att_src1 = (const float*)d_in[3];
    const float* att_dst1 = (const float*)d_in[4];
    const float* b1       = (const float*)d_in[5];
    const float* W2       = (const float*)d_in[6];
    const float* att_src2 = (const float*)d_in[7];
    const float* att_dst2 = (const float*)d_in[8];
    const float* b2       = (const float*)d_in[9];
    float* out = (float*)d_out;

    const int* src = ei;
    const int* dst = ei + N_EDGES;

    // ---- workspace carve-up (bytes); total ~39.8 MB ----
    char* ws = (char*)d_ws;
    size_t off = 0;
    unsigned short* h1 = (unsigned short*)(ws + off);
    off += (size_t)N_NODES * HID * 2;                                      // 25.6 MB
    float* a_src1 = (float*)(ws + off); off += (size_t)N_NODES * HEADS * 4;
    float* a_dst1 = (float*)(ws + off); off += (size_t)N_NODES * HEADS * 4;
    float4* pk = (float4*)(ws + off); off += (size_t)N_NODES * 16;
    float* a2d = (float*)(ws + off); off += (size_t)N_NODES * 4;
    int* deg    = (int*)(ws + off); off += (size_t)N_NODES * 4;
    unsigned short* csr = (unsigned short*)(ws + off);
    off += (size_t)N_NODES * CAPL * 2;                                     // 9.6 MB
    unsigned short* bImg  = (unsigned short*)(ws + off); off += BIMG_BYTES;  // 176 KB
    unsigned short* waImg = (unsigned short*)(ws + off); off += WAIMG_BYTES; // 22.5 KB

    hipMemsetAsync(deg, 0, (size_t)N_NODES * 4, stream);

    const int NW = (N_NODES * 64 + 255) / 256;

    // ---- prepass: W and Wa fragment-major split-bf16 images ----
    prep_kernel<<<WPB + WAB, 256, 0, stream>>>(W1, att_src1, att_dst1, bImg, waImg);

    // ---- MFMA gemm + att dots || scatter ----
    fusedAB_kernel<<<GEMM_BLOCKS + SCB, 256, 0, stream>>>(
        x, bImg, waImg, h1, a_src1, a_dst1, src, dst, deg, csr);

    // ---- layer 1 aggregate + ELU + layer 2 GEMM (fused) ----
    agg1_fused_kernel<<<NW, 256, 0, stream>>>(
        deg, csr, a_src1, a_dst1, h1, b1, W2, att_src2, att_dst2, pk, a2d);

    // ---- layer 2 aggregate ----
    agg2_fused_kernel<<<(N_NODES * 16 + 255) / 256, 256, 0, stream>>>(
        deg, csr, pk, a2d, b2, out);
}

// Round 9
// 320.846 us; speedup vs baseline: 1.0053x; 1.0053x over previous
//
#include <hip/hip_runtime.h>
#include <hip/hip_bf16.h>
#include <math.h>

#define N_NODES 50000
#define N_EDGES 1600000
#define ET (N_EDGES + N_NODES)   // with self loops
#define IN_C 165
#define HID 256
#define HEADS 8
#define C1 32
#define OUT_C 2
#define NEG_SLOPE 0.2f
#define LOG2E 1.44269504088896f
#define TROWS 32                           // gemm tile rows (mfma 32x32)
#define GEMM_BLOCKS ((N_NODES + TROWS - 1) / TROWS)  // 1563
#define SCB 2048                           // scatter blocks (8 classes x 256)
#define SGRP 256                           // scatter blocks per class
#define NPP ((N_NODES + 7) / 8)            // 6250 nodes per dst partition
#define CAPL 96                            // fixed per-node list capacity
#define NE4 (N_EDGES / 4)                  // 400000 int4-scan elements

// ---- MFMA gemm geometry ----
// K padded 165 -> 176 = 11 steps of K16 (v_mfma_f32_32x32x16_bf16).
// bf16x3 split: X*W ~= xh*wh + xh*wl + xl*wh  (xl*wl ~2^-18 rel, dropped).
#define NSTEP 11
#define BIMG_BYTES ((size_t)NSTEP * 16384)                 // 176 KB
#define WAIMG_BYTES ((size_t)NSTEP * 2048)                 // 22.5 KB
#define WT (NSTEP * 512)                   // W granules: (s, kg, nsub, col32)
#define WPB ((WT + 255) / 256)             // 22
#define WAT (176 * 16)                     // Wa dots: (k, j)
#define WAB ((WAT + 255) / 256)            // 11

typedef float f32x2 __attribute__((ext_vector_type(2)));
typedef short s16x8 __attribute__((ext_vector_type(8)));
typedef float f32x16 __attribute__((ext_vector_type(16)));

__device__ inline float lrelu(float v) { return v > 0.f ? v : NEG_SLOPE * v; }
// weight from PRE-SCALED (x log2e) logit: exp(lrelu(x)) = exp2(lrelu(x*log2e))
__device__ inline float e2l(float t) { return exp2f(fmaxf(t, NEG_SLOPE * t)); }

// fp32 -> bf16 bits, round-to-nearest-even
__device__ inline unsigned short f32_bf16(float f) {
    unsigned u = __float_as_uint(f);
    return (unsigned short)((u + 0x7FFFu + ((u >> 16) & 1u)) >> 16);
}

__device__ inline float bflo(unsigned u) { return __uint_as_float(u << 16); }
__device__ inline float bfhi(unsigned u) { return __uint_as_float(u & 0xFFFF0000u); }
__device__ inline float bf2f(unsigned short b) { return __uint_as_float(((unsigned)b) << 16); }

// ============ prepass: W fragment image + Wa (= W*att) fragment image =======
__global__ __launch_bounds__(256) void prep_kernel(
        const float* __restrict__ W,
        const float* __restrict__ att_src, const float* __restrict__ att_dst,
        unsigned short* __restrict__ bImg, unsigned short* __restrict__ waImg) {
    if (blockIdx.x < WPB) {
        int g2 = blockIdx.x * 256 + threadIdx.x;
        if (g2 >= WT) return;
        int s = g2 >> 9;
        int r9 = g2 & 511;
        int kg = r9 >> 8, nsub = (r9 >> 5) & 7, c32 = r9 & 31;
        int col = nsub * 32 + c32;
        int k0 = s * 16 + kg * 8;
        unsigned short hb[8], lb[8];
        #pragma unroll
        for (int i = 0; i < 8; ++i) {
            int k = k0 + i;
            float v = (k < IN_C) ? W[(size_t)k * HID + col] : 0.f;
            hb[i] = f32_bf16(v);
            lb[i] = f32_bf16(v - bf2f(hb[i]));
        }
        unsigned ph[4], pl[4];
        #pragma unroll
        for (int q = 0; q < 4; ++q) {
            ph[q] = (unsigned)hb[2*q] | ((unsigned)hb[2*q+1] << 16);
            pl[q] = (unsigned)lb[2*q] | ((unsigned)lb[2*q+1] << 16);
        }
        unsigned short* base = bImg + (size_t)s * 8192
                             + ((nsub * 2 + kg) * 32 + c32) * 8;
        *(uint4*)(base)        = make_uint4(ph[0], ph[1], ph[2], ph[3]);
        *(uint4*)(base + 4096) = make_uint4(pl[0], pl[1], pl[2], pl[3]);
    } else {
        int g2 = (blockIdx.x - WPB) * 256 + threadIdx.x;
        if (g2 >= WAT) return;
        int k = g2 >> 4, j = g2 & 15;
        int head = j >> 1;
        float dotv = 0.f;
        if (k < IN_C) {
            const float* wr = W + (size_t)k * HID + head * 32;
            const float* at = ((j & 1) ? att_dst : att_src) + head * 32;
            #pragma unroll
            for (int c = 0; c < 32; c += 4) {
                float4 wv = *(const float4*)(wr + c);
                float4 av = *(const float4*)(at + c);
                dotv += wv.x*av.x + wv.y*av.y + wv.z*av.z + wv.w*av.w;
            }
        }
        unsigned short dh = f32_bf16(dotv);
        unsigned short dl = f32_bf16(dotv - bf2f(dh));
        int s = k >> 4, kk = k & 15, kg = kk >> 3, i = kk & 7;
        unsigned short* base = waImg + (size_t)s * 1024 + (kg * 32 + j) * 8 + i;
        base[0]   = dh;     // split h
        base[512] = dl;     // split l
    }
}

// ============ MFMA gemm1 + fused attention-dot tiles (unchanged R7) =========
__device__ __forceinline__ void gemm_mfma_block(
        int b, const float* __restrict__ x,
        const unsigned short* __restrict__ bImg,
        const unsigned short* __restrict__ waImg,
        unsigned short* __restrict__ h, float* __restrict__ a_src,
        float* __restrict__ a_dst, unsigned short* asr) {
    const int tid = threadIdx.x;
    const int w = tid >> 6, l = tid & 63;
    const int half = l >> 5, ln = l & 31;
    const int row0 = b * TROWS;
    for (int g = tid; g < 704; g += 256) {
        int o = g >> 5, row = g & 31;
        int s = o >> 1, kg = o & 1;
        int node = row0 + row;
        int k0 = o * 8;
        unsigned short hb[8], lb[8];
        #pragma unroll
        for (int i = 0; i < 8; ++i) {
            int k = k0 + i;
            float v = (node < N_NODES && k < IN_C) ? x[(size_t)node * IN_C + k] : 0.f;
            hb[i] = f32_bf16(v);
            lb[i] = f32_bf16(v - bf2f(hb[i]));
        }
        unsigned ph[4], pl[4];
        #pragma unroll
        for (int q = 0; q < 4; ++q) {
            ph[q] = (unsigned)hb[2*q] | ((unsigned)hb[2*q+1] << 16);
            pl[q] = (unsigned)lb[2*q] | ((unsigned)lb[2*q+1] << 16);
        }
        unsigned short* base = asr + s * 1024 + (kg * 32 + row) * 8;
        *(uint4*)(base)       = make_uint4(ph[0], ph[1], ph[2], ph[3]);
        *(uint4*)(base + 512) = make_uint4(pl[0], pl[1], pl[2], pl[3]);
    }
    __syncthreads();

    f32x16 acc0, acc1, accA;
    #pragma unroll
    for (int r = 0; r < 16; ++r) { acc0[r] = 0.f; acc1[r] = 0.f; accA[r] = 0.f; }
    const int ns0 = 2 * w, ns1 = 2 * w + 1;
    const int afo = (half * 32 + ln) * 8;     // A/Wa frag offset (shorts)
    const int fo0 = ((ns0 * 2 + half) * 32 + ln) * 8;
    const int fo1 = ((ns1 * 2 + half) * 32 + ln) * 8;
    for (int s = 0; s < NSTEP; ++s) {
        const unsigned short* ab = asr + s * 1024;
        s16x8 a_h = *(const s16x8*)(ab + afo);
        s16x8 a_l = *(const s16x8*)(ab + 512 + afo);
        const unsigned short* bb = bImg + (size_t)s * 8192;
        s16x8 bh0 = *(const s16x8*)(bb + fo0);
        s16x8 bh1 = *(const s16x8*)(bb + fo1);
        s16x8 bl0 = *(const s16x8*)(bb + 4096 + fo0);
        s16x8 bl1 = *(const s16x8*)(bb + 4096 + fo1);
        acc0 = __builtin_amdgcn_mfma_f32_32x32x16_bf16(a_h, bh0, acc0, 0, 0, 0);
        acc1 = __builtin_amdgcn_mfma_f32_32x32x16_bf16(a_h, bh1, acc1, 0, 0, 0);
        acc0 = __builtin_amdgcn_mfma_f32_32x32x16_bf16(a_h, bl0, acc0, 0, 0, 0);
        acc1 = __builtin_amdgcn_mfma_f32_32x32x16_bf16(a_h, bl1, acc1, 0, 0, 0);
        acc0 = __builtin_amdgcn_mfma_f32_32x32x16_bf16(a_l, bh0, acc0, 0, 0, 0);
        acc1 = __builtin_amdgcn_mfma_f32_32x32x16_bf16(a_l, bh1, acc1, 0, 0, 0);
        if (w == 0) {                          // wave-uniform branch
            const unsigned short* wb = waImg + (size_t)s * 1024;
            s16x8 wah = *(const s16x8*)(wb + afo);
            s16x8 wal = *(const s16x8*)(wb + 512 + afo);
            accA = __builtin_amdgcn_mfma_f32_32x32x16_bf16(a_h, wah, accA, 0, 0, 0);
            accA = __builtin_amdgcn_mfma_f32_32x32x16_bf16(a_h, wal, accA, 0, 0, 0);
            accA = __builtin_amdgcn_mfma_f32_32x32x16_bf16(a_l, wah, accA, 0, 0, 0);
        }
    }
    #pragma unroll
    for (int t = 0; t < 2; ++t) {
        const int colg = w * 64 + t * 32 + ln;
        #pragma unroll
        for (int r = 0; r < 16; ++r) {
            int row = (r & 3) + 8 * (r >> 2) + 4 * half;
            int gr = row0 + row;
            if (gr < N_NODES) {
                float a = t ? acc1[r] : acc0[r];
                h[(size_t)gr * HID + colg] = f32_bf16(a);
            }
        }
    }
    if (w == 0 && ln < 16) {
        int head = ln >> 1;
        float* ap = (ln & 1) ? a_dst : a_src;
        #pragma unroll
        for (int r = 0; r < 16; ++r) {
            int row = (r & 3) + 8 * (r >> 2) + 4 * half;
            int gr = row0 + row;
            if (gr < N_NODES) ap[gr * 8 + head] = accA[r] * LOG2E;
        }
    }
}

// ============ fused: MFMA gemm || partition-filtered slotted scatter ========
__global__ __launch_bounds__(256) void fusedAB_kernel(
        const float* __restrict__ x,
        const unsigned short* __restrict__ bImg,
        const unsigned short* __restrict__ waImg,
        unsigned short* __restrict__ h, float* __restrict__ a_src,
        float* __restrict__ a_dst,
        const int* __restrict__ src, const int* __restrict__ dst,
        int* __restrict__ deg, unsigned short* __restrict__ csr) {
    __shared__ unsigned short asr[NSTEP * 1024];   // 22.5 KB A-fragment region
    if (blockIdx.x < GEMM_BLOCKS) {
        gemm_mfma_block(blockIdx.x, x, bImg, waImg, h, a_src, a_dst, asr);
    } else {
        const int sb  = blockIdx.x - GEMM_BLOCKS;   // 0..SCB-1
        const int cls = sb & 7;
        const int blk = sb >> 3;                    // 0..255 within class
        const int lo = cls * NPP;
        const int hi = (lo + NPP < N_NODES) ? lo + NPP : N_NODES;
        const int t = blk * 256 + threadIdx.x;      // 0..65535 within class
        if (t < hi - lo) {                          // self loops: direct insert
            int d = lo + t;
            int slot = atomicAdd(&deg[d], 1);
            csr[(size_t)d * CAPL + slot] = (unsigned short)d;
        }
        const int4* dst4 = (const int4*)dst;        // int4 scan of real edges
        for (int uu = t; uu < NE4; uu += SGRP * 256) {
            int4 dv = dst4[uu];
            #pragma unroll
            for (int j = 0; j < 4; ++j) {
                int d = (j == 0) ? dv.x : (j == 1) ? dv.y : (j == 2) ? dv.z : dv.w;
                if (d >= lo && d < hi) {
                    int slot = atomicAdd(&deg[d], 1);
                    csr[(size_t)d * CAPL + slot] = (unsigned short)src[4 * uu + j];
                }
            }
        }
    }
}

// ============ Layer 1 fused: softmax-aggregate(bf16 gather) + bias + ELU
//              + layer-2 GEMM.  R9: 32-edge main rounds (16 gathers in flight
//              per halfwave, 2x MLP of R8); register-resident list (4 uint4,
//              static indexing); static tails (unmasked-16 + masked-16,
//              clamp s->wid = wave-uniform L1-hit row). =====================
__global__ __launch_bounds__(256) void agg1_fused_kernel(
        const int* __restrict__ deg, const unsigned short* __restrict__ csr,
        const float* __restrict__ a_src, const float* __restrict__ a_dst,
        const unsigned short* __restrict__ h1, const float* __restrict__ bias1,
        const float* __restrict__ W2,
        const float* __restrict__ as2, const float* __restrict__ ad2,
        float4* __restrict__ pk, float* __restrict__ a2d) {
    int wid = (blockIdx.x * 256 + threadIdx.x) >> 6;
    int l = threadIdx.x & 63;
    if (wid >= N_NODES) return;
    const int el = l >> 5;                    // edge parity (half-wave)
    const int q  = l & 31;                    // channel octet id
    const int hd = q >> 2;                    // head
    const int ch = q * 8;                     // ushort offset (16 B per lane)
    const int sh = el * 16;                   // halfword select shift
    const uint4* lst4 = (const uint4*)(csr + (size_t)wid * CAPL);
    const int n = deg[wid];
    const float ad_p = a_dst[wid * 8 + hd];
    float den = 0.f;
    f32x2 ac0 = {0.f, 0.f}, ac1 = {0.f, 0.f}, ac2 = {0.f, 0.f}, ac3 = {0.f, 0.f};

    // register-resident edge window: edges i .. i+31 in ca..cd
    uint4 ca = lst4[0], cb = lst4[1], cc = lst4[2], cd = lst4[3];
    int i = 0;

#define EXTRACT_S(S_, MK_, OFF_, W0_, W1_, W2_, W3_, W4_, W5_, W6_, W7_)      \
    {                                                                          \
        unsigned wsel_[8] = {W0_, W1_, W2_, W3_, W4_, W5_, W6_, W7_};          \
        _Pragma("unroll")                                                      \
        for (int j = 0; j < 8; ++j) {                                          \
            int sv = (int)((wsel_[j] >> sh) & 0xFFFFu);                        \
            int e = i + OFF_ + 2 * j + el;                                     \
            bool ok = e < n;                                                   \
            MK_[j] = ok ? 1.f : 0.f;                                           \
            S_[j] = ok ? sv : wid;                                             \
        }                                                                      \
    }

#define GATHER_ACC(S_, MK_, CNT_)                                              \
    {                                                                          \
        uint4 v_[CNT_];                                                        \
        _Pragma("unroll")                                                      \
        for (int j = 0; j < CNT_; ++j)                                         \
            v_[j] = *(const uint4*)(h1 + (size_t)S_[j] * HID + ch);            \
        float w_[CNT_];                                                        \
        _Pragma("unroll")                                                      \
        for (int j = 0; j < CNT_; ++j)                                         \
            w_[j] = MK_[j] * e2l(a_src[S_[j] * 8 + hd] + ad_p);                \
        _Pragma("unroll")                                                      \
        for (int j = 0; j < CNT_; ++j) {                                       \
            den += w_[j];                                                      \
            f32x2 w2_ = {w_[j], w_[j]};                                        \
            ac0 += w2_ * (f32x2){bflo(v_[j].x), bfhi(v_[j].x)};                \
            ac1 += w2_ * (f32x2){bflo(v_[j].y), bfhi(v_[j].y)};                \
            ac2 += w2_ * (f32x2){bflo(v_[j].z), bfhi(v_[j].z)};                \
            ac3 += w2_ * (f32x2){bflo(v_[j].w), bfhi(v_[j].w)};                \
        }                                                                      \
    }

    // main: 32 edges per round, 16 gathers in flight per halfwave
    for (; i + 32 <= n; i += 32) {
        uint4 na = ca, nb = cb, nc = cc, nd = cd;
        if (i + 32 < n) {                     // prefetch next 32-edge window
            na = lst4[(i >> 3) + 4]; nb = lst4[(i >> 3) + 5];
            nc = lst4[(i >> 3) + 6]; nd = lst4[(i >> 3) + 7];
        }
        int s[16]; float mk[16];
        EXTRACT_S(s, mk, 0,  ca.x, ca.y, ca.z, ca.w, cb.x, cb.y, cb.z, cb.w)
        EXTRACT_S((s + 8), (mk + 8), 16, cc.x, cc.y, cc.z, cc.w, cd.x, cd.y, cd.z, cd.w)
        GATHER_ACC(s, mk, 16)
        ca = na; cb = nb; cc = nc; cd = nd;
    }
    // tail A: unmasked 16 if it fits (edges i..i+15 in ca,cb)
    if (i + 16 <= n) {
        int s[8]; float mk[8];
        EXTRACT_S(s, mk, 0, ca.x, ca.y, ca.z, ca.w, cb.x, cb.y, cb.z, cb.w)
        GATHER_ACC(s, mk, 8)
        ca = cc; cb = cd;                     // shift window (static names)
        i += 16;
    }
    // tail B: masked 16 (clamped slots hit the wave-uniform wid row)
    if (i < n) {
        int s[8]; float mk[8];
        EXTRACT_S(s, mk, 0, ca.x, ca.y, ca.z, ca.w, cb.x, cb.y, cb.z, cb.w)
        GATHER_ACC(s, mk, 8)
    }
#undef EXTRACT_S
#undef GATHER_ACC

    float accs[8] = {ac0.x, ac0.y, ac1.x, ac1.y, ac2.x, ac2.y, ac3.x, ac3.y};
    den += __shfl_xor(den, 32);
    #pragma unroll
    for (int k = 0; k < 8; ++k) accs[k] += __shfl_xor(accs[k], 32);

    const float inv = 1.f / den;
    float4 bva = *(const float4*)(bias1 + ch);
    float4 bvb = *(const float4*)(bias1 + ch + 4);
    float o[8];
    o[0] = accs[0] * inv + bva.x; o[1] = accs[1] * inv + bva.y;
    o[2] = accs[2] * inv + bva.z; o[3] = accs[3] * inv + bva.w;
    o[4] = accs[4] * inv + bvb.x; o[5] = accs[5] * inv + bvb.y;
    o[6] = accs[6] * inv + bvb.z; o[7] = accs[7] * inv + bvb.w;
    #pragma unroll
    for (int k = 0; k < 8; ++k)               // ELU; exp-1 abs err ~1e-7 << tol
        o[k] = o[k] > 0.f ? o[k] : (__expf(o[k]) - 1.f);
    const float* wv = W2 + q * 16;
    float4 w0 = *(const float4*)(wv);
    float4 w1 = *(const float4*)(wv + 4);
    float4 w2 = *(const float4*)(wv + 8);
    float4 w3 = *(const float4*)(wv + 12);
    float p0 = o[0]*w0.x + o[1]*w0.z + o[2]*w1.x + o[3]*w1.z
             + o[4]*w2.x + o[5]*w2.z + o[6]*w3.x + o[7]*w3.z;
    float p1 = o[0]*w0.y + o[1]*w0.w + o[2]*w1.y + o[3]*w1.w
             + o[4]*w2.y + o[5]*w2.w + o[6]*w3.y + o[7]*w3.w;
    #pragma unroll
    for (int off = 16; off; off >>= 1) {
        p0 += __shfl_xor(p0, off);
        p1 += __shfl_xor(p1, off);
    }
    if (l == 0) {
        pk[wid] = make_float4(p0, p1, (p0 * as2[0] + p1 * as2[1]) * LOG2E, 0.f);
        a2d[wid] = (p0 * ad2[0] + p1 * ad2[1]) * LOG2E;
    }
}

// ============ Layer 2 fused (unchanged) ============
__global__ __launch_bounds__(256) void agg2_fused_kernel(
        const int* __restrict__ deg, const unsigned short* __restrict__ csr,
        const float4* __restrict__ pk, const float* __restrict__ a2d,
        const float* __restrict__ b2, float* __restrict__ out) {
    int t = blockIdx.x * 256 + threadIdx.x;
    int node = t >> 4;
    int l = t & 15;
    if (node >= N_NODES) return;
    const unsigned short* lst = csr + (size_t)node * CAPL;
    const int n = deg[node];
    const float adv = a2d[node];
    float sm = 0.f, acc0 = 0.f, acc1 = 0.f;
    for (int i = l; i < n; i += 64) {
        int s[4]; float mk[4];
        #pragma unroll
        for (int j = 0; j < 4; ++j) {
            int e = i + 16 * j;
            mk[j] = (e < n) ? 1.f : 0.f;
            s[j] = lst[(e < n) ? e : (n - 1)];
        }
        float4 pv[4];
        #pragma unroll
        for (int j = 0; j < 4; ++j) pv[j] = pk[s[j]];
        #pragma unroll
        for (int j = 0; j < 4; ++j) {
            float w = mk[j] * e2l(pv[j].z + adv);
            sm += w;
            acc0 += w * pv[j].x;
            acc1 += w * pv[j].y;
        }
    }
    #pragma unroll
    for (int off = 8; off; off >>= 1) {
        sm   += __shfl_xor(sm, off);
        acc0 += __shfl_xor(acc0, off);
        acc1 += __shfl_xor(acc1, off);
    }
    if (l == 0) {
        *(float2*)(out + node * 2) =
            make_float2(acc0 / sm + b2[0], acc1 / sm + b2[1]);
    }
}

extern "C" void kernel_launch(void* const* d_in, const int* in_sizes, int n_in,
                              void* d_out, int out_size, void* d_ws, size_t ws_size,
                              hipStream_t stream) {
    (void)in_sizes; (void)n_in; (void)out_size; (void)ws_size;
    const float* x        = (const float*)d_in[0];
    const int*   ei       = (const int*)d_in[1];
    const float* W1       = (const float*)d_in[2];
    const float* att_src1 = (const float*)d_in[3];
    const float* att_dst1 = (const float*)d_in[4];
    const float* b1       = (const float*)d_in[5];
    const float* W2       = (const float*)d_in[6];
    const float* att_src2 = (const float*)d_in[7];
    const float* att_dst2 = (const float*)d_in[8];
    const float* b2       = (const float*)d_in[9];
    float* out = (float*)d_out;

    const int* src = ei;
    const int* dst = ei + N_EDGES;

    // ---- workspace carve-up (bytes); total ~39.8 MB ----
    char* ws = (char*)d_ws;
    size_t off = 0;
    unsigned short* h1 = (unsigned short*)(ws + off);
    off += (size_t)N_NODES * HID * 2;                                      // 25.6 MB
    float* a_src1 = (float*)(ws + off); off += (size_t)N_NODES * HEADS * 4;
    float* a_dst1 = (float*)(ws + off); off += (size_t)N_NODES * HEADS * 4;
    float4* pk = (float4*)(ws + off); off += (size_t)N_NODES * 16;
    float* a2d = (float*)(ws + off); off += (size_t)N_NODES * 4;
    int* deg    = (int*)(ws + off); off += (size_t)N_NODES * 4;
    unsigned short* csr = (unsigned short*)(ws + off);
    off += (size_t)N_NODES * CAPL * 2;                                     // 9.6 MB
    unsigned short* bImg  = (unsigned short*)(ws + off); off += BIMG_BYTES;  // 176 KB
    unsigned short* waImg = (unsigned short*)(ws + off); off += WAIMG_BYTES; // 22.5 KB

    hipMemsetAsync(deg, 0, (size_t)N_NODES * 4, stream);

    const int NW = (N_NODES * 64 + 255) / 256;

    // ---- prepass: W and Wa fragment-major split-bf16 images ----
    prep_kernel<<<WPB + WAB, 256, 0, stream>>>(W1, att_src1, att_dst1, bImg, waImg);

    // ---- MFMA gemm + att dots || scatter ----
    fusedAB_kernel<<<GEMM_BLOCKS + SCB, 256, 0, stream>>>(
        x, bImg, waImg, h1, a_src1, a_dst1, src, dst, deg, csr);

    // ---- layer 1 aggregate + ELU + layer 2 GEMM (fused) ----
    agg1_fused_kernel<<<NW, 256, 0, stream>>>(
        deg, csr, a_src1, a_dst1, h1, b1, W2, att_src2, att_dst2, pk, a2d);

    // ---- layer 2 aggregate ----
    agg2_fused_kernel<<<(N_NODES * 16 + 255) / 256, 256, 0, stream>>>(
        deg, csr, pk, a2d, b2, out);
}

// Round 10
// 318.118 us; speedup vs baseline: 1.0139x; 1.0086x over previous
//
#include <hip/hip_runtime.h>
#include <hip/hip_bf16.h>
#include <math.h>

#define N_NODES 50000
#define N_EDGES 1600000
#define IN_C 165
#define HID 256
#define HEADS 8
#define C1 32
#define OUT_C 2
#define NEG_SLOPE 0.2f
#define LOG2E 1.44269504088896f
#define TROWS 32                           // gemm tile rows (mfma 32x32)
#define GEMM_BLOCKS ((N_NODES + TROWS - 1) / TROWS)  // 1563
#define SCB 2048                           // scatter blocks (8 classes x 256)
#define SGRP 256                           // scatter blocks per class
#define NPP ((N_NODES + 7) / 8)            // 6250 nodes per dst partition
#define CAPL 96                            // fixed per-node list capacity
#define NE4 (N_EDGES / 4)                  // 400000 int4-scan elements

// ---- MFMA gemm geometry (R7, unchanged) ----
#define NSTEP 11
#define BIMG_BYTES ((size_t)NSTEP * 16384)                 // 176 KB
#define WAIMG_BYTES ((size_t)NSTEP * 2048)                 // 22.5 KB
#define WT (NSTEP * 512)
#define WPB ((WT + 255) / 256)             // 22
#define WAT (176 * 16)
#define WAB ((WAT + 255) / 256)            // 11

typedef float f32x2 __attribute__((ext_vector_type(2)));
typedef short s16x8 __attribute__((ext_vector_type(8)));
typedef float f32x16 __attribute__((ext_vector_type(16)));

__device__ inline float lrelu(float v) { return v > 0.f ? v : NEG_SLOPE * v; }
// weight from PRE-SCALED (x log2e) logit: exp(lrelu(x)) = exp2(lrelu(x*log2e))
__device__ inline float e2l(float t) { return exp2f(fmaxf(t, NEG_SLOPE * t)); }

// fp32 -> bf16 bits, round-to-nearest-even
__device__ inline unsigned short f32_bf16(float f) {
    unsigned u = __float_as_uint(f);
    return (unsigned short)((u + 0x7FFFu + ((u >> 16) & 1u)) >> 16);
}

__device__ inline float bflo(unsigned u) { return __uint_as_float(u << 16); }
__device__ inline float bfhi(unsigned u) { return __uint_as_float(u & 0xFFFF0000u); }
__device__ inline float bf2f(unsigned short b) { return __uint_as_float(((unsigned)b) << 16); }

// ============ prepass: W fragment image + Wa (= W*att) fragment image =======
__global__ __launch_bounds__(256) void prep_kernel(
        const float* __restrict__ W,
        const float* __restrict__ att_src, const float* __restrict__ att_dst,
        unsigned short* __restrict__ bImg, unsigned short* __restrict__ waImg) {
    if (blockIdx.x < WPB) {
        int g2 = blockIdx.x * 256 + threadIdx.x;
        if (g2 >= WT) return;
        int s = g2 >> 9;
        int r9 = g2 & 511;
        int kg = r9 >> 8, nsub = (r9 >> 5) & 7, c32 = r9 & 31;
        int col = nsub * 32 + c32;
        int k0 = s * 16 + kg * 8;
        unsigned short hb[8], lb[8];
        #pragma unroll
        for (int i = 0; i < 8; ++i) {
            int k = k0 + i;
            float v = (k < IN_C) ? W[(size_t)k * HID + col] : 0.f;
            hb[i] = f32_bf16(v);
            lb[i] = f32_bf16(v - bf2f(hb[i]));
        }
        unsigned ph[4], pl[4];
        #pragma unroll
        for (int q = 0; q < 4; ++q) {
            ph[q] = (unsigned)hb[2*q] | ((unsigned)hb[2*q+1] << 16);
            pl[q] = (unsigned)lb[2*q] | ((unsigned)lb[2*q+1] << 16);
        }
        unsigned short* base = bImg + (size_t)s * 8192
                             + ((nsub * 2 + kg) * 32 + c32) * 8;
        *(uint4*)(base)        = make_uint4(ph[0], ph[1], ph[2], ph[3]);
        *(uint4*)(base + 4096) = make_uint4(pl[0], pl[1], pl[2], pl[3]);
    } else {
        int g2 = (blockIdx.x - WPB) * 256 + threadIdx.x;
        if (g2 >= WAT) return;
        int k = g2 >> 4, j = g2 & 15;
        int head = j >> 1;
        float dotv = 0.f;
        if (k < IN_C) {
            const float* wr = W + (size_t)k * HID + head * 32;
            const float* at = ((j & 1) ? att_dst : att_src) + head * 32;
            #pragma unroll
            for (int c = 0; c < 32; c += 4) {
                float4 wv = *(const float4*)(wr + c);
                float4 av = *(const float4*)(at + c);
                dotv += wv.x*av.x + wv.y*av.y + wv.z*av.z + wv.w*av.w;
            }
        }
        unsigned short dh = f32_bf16(dotv);
        unsigned short dl = f32_bf16(dotv - bf2f(dh));
        int s = k >> 4, kk = k & 15, kg = kk >> 3, i = kk & 7;
        unsigned short* base = waImg + (size_t)s * 1024 + (kg * 32 + j) * 8 + i;
        base[0]   = dh;     // split h
        base[512] = dl;     // split l
    }
}

// ============ MFMA gemm1 + fused attention-dot tiles (unchanged R7) =========
__device__ __forceinline__ void gemm_mfma_block(
        int b, const float* __restrict__ x,
        const unsigned short* __restrict__ bImg,
        const unsigned short* __restrict__ waImg,
        unsigned short* __restrict__ h, float* __restrict__ a_src,
        float* __restrict__ a_dst, unsigned short* asr) {
    const int tid = threadIdx.x;
    const int w = tid >> 6, l = tid & 63;
    const int half = l >> 5, ln = l & 31;
    const int row0 = b * TROWS;
    for (int g = tid; g < 704; g += 256) {
        int o = g >> 5, row = g & 31;
        int s = o >> 1, kg = o & 1;
        int node = row0 + row;
        int k0 = o * 8;
        unsigned short hb[8], lb[8];
        #pragma unroll
        for (int i = 0; i < 8; ++i) {
            int k = k0 + i;
            float v = (node < N_NODES && k < IN_C) ? x[(size_t)node * IN_C + k] : 0.f;
            hb[i] = f32_bf16(v);
            lb[i] = f32_bf16(v - bf2f(hb[i]));
        }
        unsigned ph[4], pl[4];
        #pragma unroll
        for (int q = 0; q < 4; ++q) {
            ph[q] = (unsigned)hb[2*q] | ((unsigned)hb[2*q+1] << 16);
            pl[q] = (unsigned)lb[2*q] | ((unsigned)lb[2*q+1] << 16);
        }
        unsigned short* base = asr + s * 1024 + (kg * 32 + row) * 8;
        *(uint4*)(base)       = make_uint4(ph[0], ph[1], ph[2], ph[3]);
        *(uint4*)(base + 512) = make_uint4(pl[0], pl[1], pl[2], pl[3]);
    }
    __syncthreads();

    f32x16 acc0, acc1, accA;
    #pragma unroll
    for (int r = 0; r < 16; ++r) { acc0[r] = 0.f; acc1[r] = 0.f; accA[r] = 0.f; }
    const int ns0 = 2 * w, ns1 = 2 * w + 1;
    const int afo = (half * 32 + ln) * 8;     // A/Wa frag offset (shorts)
    const int fo0 = ((ns0 * 2 + half) * 32 + ln) * 8;
    const int fo1 = ((ns1 * 2 + half) * 32 + ln) * 8;
    for (int s = 0; s < NSTEP; ++s) {
        const unsigned short* ab = asr + s * 1024;
        s16x8 a_h = *(const s16x8*)(ab + afo);
        s16x8 a_l = *(const s16x8*)(ab + 512 + afo);
        const unsigned short* bb = bImg + (size_t)s * 8192;
        s16x8 bh0 = *(const s16x8*)(bb + fo0);
        s16x8 bh1 = *(const s16x8*)(bb + fo1);
        s16x8 bl0 = *(const s16x8*)(bb + 4096 + fo0);
        s16x8 bl1 = *(const s16x8*)(bb + 4096 + fo1);
        acc0 = __builtin_amdgcn_mfma_f32_32x32x16_bf16(a_h, bh0, acc0, 0, 0, 0);
        acc1 = __builtin_amdgcn_mfma_f32_32x32x16_bf16(a_h, bh1, acc1, 0, 0, 0);
        acc0 = __builtin_amdgcn_mfma_f32_32x32x16_bf16(a_h, bl0, acc0, 0, 0, 0);
        acc1 = __builtin_amdgcn_mfma_f32_32x32x16_bf16(a_h, bl1, acc1, 0, 0, 0);
        acc0 = __builtin_amdgcn_mfma_f32_32x32x16_bf16(a_l, bh0, acc0, 0, 0, 0);
        acc1 = __builtin_amdgcn_mfma_f32_32x32x16_bf16(a_l, bh1, acc1, 0, 0, 0);
        if (w == 0) {                          // wave-uniform branch
            const unsigned short* wb = waImg + (size_t)s * 1024;
            s16x8 wah = *(const s16x8*)(wb + afo);
            s16x8 wal = *(const s16x8*)(wb + 512 + afo);
            accA = __builtin_amdgcn_mfma_f32_32x32x16_bf16(a_h, wah, accA, 0, 0, 0);
            accA = __builtin_amdgcn_mfma_f32_32x32x16_bf16(a_h, wal, accA, 0, 0, 0);
            accA = __builtin_amdgcn_mfma_f32_32x32x16_bf16(a_l, wah, accA, 0, 0, 0);
        }
    }
    #pragma unroll
    for (int t = 0; t < 2; ++t) {
        const int colg = w * 64 + t * 32 + ln;
        #pragma unroll
        for (int r = 0; r < 16; ++r) {
            int row = (r & 3) + 8 * (r >> 2) + 4 * half;
            int gr = row0 + row;
            if (gr < N_NODES) {
                float a = t ? acc1[r] : acc0[r];
                h[(size_t)gr * HID + colg] = f32_bf16(a);
            }
        }
    }
    if (w == 0 && ln < 16) {
        int head = ln >> 1;
        float* ap = (ln & 1) ? a_dst : a_src;
        #pragma unroll
        for (int r = 0; r < 16; ++r) {
            int row = (r & 3) + 8 * (r >> 2) + 4 * half;
            int gr = row0 + row;
            if (gr < N_NODES) ap[gr * 8 + head] = accA[r] * LOG2E;
        }
    }
}

// ============ fused: MFMA gemm || partition-filtered slotted scatter ========
// R10: self-loops NO LONGER inserted (added analytically in agg1/agg2) —
// saves 50K atomics and a branch; csr holds only real edges.
__global__ __launch_bounds__(256) void fusedAB_kernel(
        const float* __restrict__ x,
        const unsigned short* __restrict__ bImg,
        const unsigned short* __restrict__ waImg,
        unsigned short* __restrict__ h, float* __restrict__ a_src,
        float* __restrict__ a_dst,
        const int* __restrict__ src, const int* __restrict__ dst,
        int* __restrict__ deg, unsigned short* __restrict__ csr) {
    __shared__ unsigned short asr[NSTEP * 1024];   // 22.5 KB A-fragment region
    if (blockIdx.x < GEMM_BLOCKS) {
        gemm_mfma_block(blockIdx.x, x, bImg, waImg, h, a_src, a_dst, asr);
    } else {
        const int sb  = blockIdx.x - GEMM_BLOCKS;   // 0..SCB-1
        const int cls = sb & 7;
        const int blk = sb >> 3;                    // 0..255 within class
        const int lo = cls * NPP;
        const int hi = (lo + NPP < N_NODES) ? lo + NPP : N_NODES;
        const int t = blk * 256 + threadIdx.x;      // 0..65535 within class
        const int4* dst4 = (const int4*)dst;        // int4 scan of real edges
        for (int uu = t; uu < NE4; uu += SGRP * 256) {
            int4 dv = dst4[uu];
            #pragma unroll
            for (int j = 0; j < 4; ++j) {
                int d = (j == 0) ? dv.x : (j == 1) ? dv.y : (j == 2) ? dv.z : dv.w;
                if (d >= lo && d < hi) {
                    int slot = atomicAdd(&deg[d], 1);
                    csr[(size_t)d * CAPL + slot] = (unsigned short)src[4 * uu + j];
                }
            }
        }
    }
}

// ============ Layer 1 fused: softmax-aggregate(bf16 gather) + bias + ELU
//              + layer-2 GEMM.  R10: self-loop term added analytically
//              post-combine (wave-uniform h1[wid] row). Loop = R9 structure.
__global__ __launch_bounds__(256) void agg1_fused_kernel(
        const int* __restrict__ deg, const unsigned short* __restrict__ csr,
        const float* __restrict__ a_src, const float* __restrict__ a_dst,
        const unsigned short* __restrict__ h1, const float* __restrict__ bias1,
        const float* __restrict__ W2,
        const float* __restrict__ as2, const float* __restrict__ ad2,
        float4* __restrict__ pk, float* __restrict__ a2d) {
    int wid = (blockIdx.x * 256 + threadIdx.x) >> 6;
    int l = threadIdx.x & 63;
    if (wid >= N_NODES) return;
    const int el = l >> 5;                    // edge parity (half-wave)
    const int q  = l & 31;                    // channel octet id
    const int hd = q >> 2;                    // head
    const int ch = q * 8;                     // ushort offset (16 B per lane)
    const int sh = el * 16;                   // halfword select shift
    const uint4* lst4 = (const uint4*)(csr + (size_t)wid * CAPL);
    const int n = deg[wid];
    const float ad_p = a_dst[wid * 8 + hd];
    float den = 0.f;
    f32x2 ac0 = {0.f, 0.f}, ac1 = {0.f, 0.f}, ac2 = {0.f, 0.f}, ac3 = {0.f, 0.f};

    uint4 ca = lst4[0], cb = lst4[1], cc = lst4[2], cd = lst4[3];
    int i = 0;

#define EXTRACT_S(S_, MK_, OFF_, W0_, W1_, W2_, W3_, W4_, W5_, W6_, W7_)      \
    {                                                                          \
        unsigned wsel_[8] = {W0_, W1_, W2_, W3_, W4_, W5_, W6_, W7_};          \
        _Pragma("unroll")                                                      \
        for (int j = 0; j < 8; ++j) {                                          \
            int sv = (int)((wsel_[j] >> sh) & 0xFFFFu);                        \
            int e = i + OFF_ + 2 * j + el;                                     \
            bool ok = e < n;                                                   \
            MK_[j] = ok ? 1.f : 0.f;                                           \
            S_[j] = ok ? sv : wid;                                             \
        }                                                                      \
    }

#define GATHER_ACC(S_, MK_, CNT_)                                              \
    {                                                                          \
        uint4 v_[CNT_];                                                        \
        _Pragma("unroll")                                                      \
        for (int j = 0; j < CNT_; ++j)                                         \
            v_[j] = *(const uint4*)(h1 + (size_t)S_[j] * HID + ch);            \
        float w_[CNT_];                                                        \
        _Pragma("unroll")                                                      \
        for (int j = 0; j < CNT_; ++j)                                         \
            w_[j] = MK_[j] * e2l(a_src[S_[j] * 8 + hd] + ad_p);                \
        _Pragma("unroll")                                                      \
        for (int j = 0; j < CNT_; ++j) {                                       \
            den += w_[j];                                                      \
            f32x2 w2_ = {w_[j], w_[j]};                                        \
            ac0 += w2_ * (f32x2){bflo(v_[j].x), bfhi(v_[j].x)};                \
            ac1 += w2_ * (f32x2){bflo(v_[j].y), bfhi(v_[j].y)};                \
            ac2 += w2_ * (f32x2){bflo(v_[j].z), bfhi(v_[j].z)};                \
            ac3 += w2_ * (f32x2){bflo(v_[j].w), bfhi(v_[j].w)};                \
        }                                                                      \
    }

    for (; i + 32 <= n; i += 32) {
        uint4 na = ca, nb = cb, nc = cc, nd = cd;
        if (i + 32 < n) {
            na = lst4[(i >> 3) + 4]; nb = lst4[(i >> 3) + 5];
            nc = lst4[(i >> 3) + 6]; nd = lst4[(i >> 3) + 7];
        }
        int s[16]; float mk[16];
        EXTRACT_S(s, mk, 0,  ca.x, ca.y, ca.z, ca.w, cb.x, cb.y, cb.z, cb.w)
        EXTRACT_S((s + 8), (mk + 8), 16, cc.x, cc.y, cc.z, cc.w, cd.x, cd.y, cd.z, cd.w)
        GATHER_ACC(s, mk, 16)
        ca = na; cb = nb; cc = nc; cd = nd;
    }
    if (i + 16 <= n) {
        int s[8]; float mk[8];
        EXTRACT_S(s, mk, 0, ca.x, ca.y, ca.z, ca.w, cb.x, cb.y, cb.z, cb.w)
        GATHER_ACC(s, mk, 8)
        ca = cc; cb = cd;
        i += 16;
    }
    if (i < n) {
        int s[8]; float mk[8];
        EXTRACT_S(s, mk, 0, ca.x, ca.y, ca.z, ca.w, cb.x, cb.y, cb.z, cb.w)
        GATHER_ACC(s, mk, 8)
    }
#undef EXTRACT_S
#undef GATHER_ACC

    float accs[8] = {ac0.x, ac0.y, ac1.x, ac1.y, ac2.x, ac2.y, ac3.x, ac3.y};
    den += __shfl_xor(den, 32);
    #pragma unroll
    for (int k = 0; k < 8; ++k) accs[k] += __shfl_xor(accs[k], 32);

    // ---- explicit self-loop term (removed from csr in R10) ----
    {
        float wsf = e2l(a_src[wid * 8 + hd] + ad_p);
        uint4 v = *(const uint4*)(h1 + (size_t)wid * HID + ch);
        den += wsf;
        accs[0] += wsf * bflo(v.x); accs[1] += wsf * bfhi(v.x);
        accs[2] += wsf * bflo(v.y); accs[3] += wsf * bfhi(v.y);
        accs[4] += wsf * bflo(v.z); accs[5] += wsf * bfhi(v.z);
        accs[6] += wsf * bflo(v.w); accs[7] += wsf * bfhi(v.w);
    }

    const float inv = 1.f / den;
    float4 bva = *(const float4*)(bias1 + ch);
    float4 bvb = *(const float4*)(bias1 + ch + 4);
    float o[8];
    o[0] = accs[0] * inv + bva.x; o[1] = accs[1] * inv + bva.y;
    o[2] = accs[2] * inv + bva.z; o[3] = accs[3] * inv + bva.w;
    o[4] = accs[4] * inv + bvb.x; o[5] = accs[5] * inv + bvb.y;
    o[6] = accs[6] * inv + bvb.z; o[7] = accs[7] * inv + bvb.w;
    #pragma unroll
    for (int k = 0; k < 8; ++k)               // ELU; exp-1 abs err ~1e-7 << tol
        o[k] = o[k] > 0.f ? o[k] : (__expf(o[k]) - 1.f);
    const float* wv = W2 + q * 16;
    float4 w0 = *(const float4*)(wv);
    float4 w1 = *(const float4*)(wv + 4);
    float4 w2 = *(const float4*)(wv + 8);
    float4 w3 = *(const float4*)(wv + 12);
    float p0 = o[0]*w0.x + o[1]*w0.z + o[2]*w1.x + o[3]*w1.z
             + o[4]*w2.x + o[5]*w2.z + o[6]*w3.x + o[7]*w3.z;
    float p1 = o[0]*w0.y + o[1]*w0.w + o[2]*w1.y + o[3]*w1.w
             + o[4]*w2.y + o[5]*w2.w + o[6]*w3.y + o[7]*w3.w;
    #pragma unroll
    for (int off = 16; off; off >>= 1) {
        p0 += __shfl_xor(p0, off);
        p1 += __shfl_xor(p1, off);
    }
    if (l == 0) {
        pk[wid] = make_float4(p0, p1, (p0 * as2[0] + p1 * as2[1]) * LOG2E, 0.f);
        a2d[wid] = (p0 * ad2[0] + p1 * ad2[1]) * LOG2E;
    }
}

// ============ Layer 2 fused: 16 lanes per node, 2-deep rounds (R10).
// Masked slots clamp to `node` (uniform, cache-hit) — R9's lst[n-1] clamp
// generated real random gathers for dead lanes. Self term added at l==0. ====
__global__ __launch_bounds__(256) void agg2_fused_kernel(
        const int* __restrict__ deg, const unsigned short* __restrict__ csr,
        const float4* __restrict__ pk, const float* __restrict__ a2d,
        const float* __restrict__ b2, float* __restrict__ out) {
    int t = blockIdx.x * 256 + threadIdx.x;
    int node = t >> 4;
    int l = t & 15;
    if (node >= N_NODES) return;
    const unsigned short* lst = csr + (size_t)node * CAPL;
    const int n = deg[node];
    const float adv = a2d[node];
    float sm = 0.f, acc0 = 0.f, acc1 = 0.f;
    for (int i = l; i < n; i += 32) {
        int s0 = lst[i];
        int e1 = i + 16;
        bool ok1 = e1 < n;
        float m1 = ok1 ? 1.f : 0.f;
        int s1 = ok1 ? lst[e1] : node;
        float4 p0 = pk[s0], p1 = pk[s1];
        float w0 = e2l(p0.z + adv);
        float w1 = m1 * e2l(p1.z + adv);
        sm += w0 + w1;
        acc0 += w0 * p0.x + w1 * p1.x;
        acc1 += w0 * p0.y + w1 * p1.y;
    }
    #pragma unroll
    for (int off = 8; off; off >>= 1) {       // xor stays within the 16-group
        sm   += __shfl_xor(sm, off);
        acc0 += __shfl_xor(acc0, off);
        acc1 += __shfl_xor(acc1, off);
    }
    if (l == 0) {
        // explicit self-loop term
        float4 ps = pk[node];
        float wsf = e2l(ps.z + adv);
        sm += wsf;
        acc0 += wsf * ps.x;
        acc1 += wsf * ps.y;
        *(float2*)(out + node * 2) =
            make_float2(acc0 / sm + b2[0], acc1 / sm + b2[1]);
    }
}

extern "C" void kernel_launch(void* const* d_in, const int* in_sizes, int n_in,
                              void* d_out, int out_size, void* d_ws, size_t ws_size,
                              hipStream_t stream) {
    (void)in_sizes; (void)n_in; (void)out_size; (void)ws_size;
    const float* x        = (const float*)d_in[0];
    const int*   ei       = (const int*)d_in[1];
    const float* W1       = (const float*)d_in[2];
    const float* att_src1 = (const float*)d_in[3];
    const float* att_dst1 = (const float*)d_in[4];
    const float* b1       = (const float*)d_in[5];
    const float* W2       = (const float*)d_in[6];
    const float* att_src2 = (const float*)d_in[7];
    const float* att_dst2 = (const float*)d_in[8];
    const float* b2       = (const float*)d_in[9];
    float* out = (float*)d_out;

    const int* src = ei;
    const int* dst = ei + N_EDGES;

    // ---- workspace carve-up (bytes); total ~39.8 MB ----
    char* ws = (char*)d_ws;
    size_t off = 0;
    unsigned short* h1 = (unsigned short*)(ws + off);
    off += (size_t)N_NODES * HID * 2;                                      // 25.6 MB
    float* a_src1 = (float*)(ws + off); off += (size_t)N_NODES * HEADS * 4;
    float* a_dst1 = (float*)(ws + off); off += (size_t)N_NODES * HEADS * 4;
    float4* pk = (float4*)(ws + off); off += (size_t)N_NODES * 16;
    float* a2d = (float*)(ws + off); off += (size_t)N_NODES * 4;
    int* deg    = (int*)(ws + off); off += (size_t)N_NODES * 4;
    unsigned short* csr = (unsigned short*)(ws + off);
    off += (size_t)N_NODES * CAPL * 2;                                     // 9.6 MB
    unsigned short* bImg  = (unsigned short*)(ws + off); off += BIMG_BYTES;  // 176 KB
    unsigned short* waImg = (unsigned short*)(ws + off); off += WAIMG_BYTES; // 22.5 KB

    hipMemsetAsync(deg, 0, (size_t)N_NODES * 4, stream);

    const int NW = (N_NODES * 64 + 255) / 256;

    // ---- prepass: W and Wa fragment-major split-bf16 images ----
    prep_kernel<<<WPB + WAB, 256, 0, stream>>>(W1, att_src1, att_dst1, bImg, waImg);

    // ---- MFMA gemm + att dots || scatter (no self-loops) ----
    fusedAB_kernel<<<GEMM_BLOCKS + SCB, 256, 0, stream>>>(
        x, bImg, waImg, h1, a_src1, a_dst1, src, dst, deg, csr);

    // ---- layer 1 aggregate + ELU + layer 2 GEMM (fused) ----
    agg1_fused_kernel<<<NW, 256, 0, stream>>>(
        deg, csr, a_src1, a_dst1, h1, b1, W2, att_src2, att_dst2, pk, a2d);

    // ---- layer 2 aggregate ----
    agg2_fused_kernel<<<(N_NODES * 16 + 255) / 256, 256, 0, stream>>>(
        deg, csr, pk, a2d, b2, out);
}